// Round 15
// baseline (347.920 us; speedup 1.0000x reference)
//
#include <hip/hip_runtime.h>
#include <cstddef>
#include <cstdint>

#define B_DIM 8
#define T_SEQ 4096
#define C_DIM 768
#define M_ROWS (B_DIM * T_SEQ)   // 32768
#define CC (C_DIM * C_DIM)       // 589824
#define NCH 32
#define CHL (T_SEQ / NCH)        // 128

using bf16x8 = __attribute__((ext_vector_type(8))) short;
using f32x4  = __attribute__((ext_vector_type(4))) float;

static __device__ __forceinline__ unsigned short f2bf(float f) {
  unsigned int u = __float_as_uint(f);
  return (unsigned short)((u + 0x7fffu + ((u >> 16) & 1u)) >> 16);
}
static __device__ __forceinline__ float bf2f(unsigned short s) {
  return __uint_as_float(((unsigned int)s) << 16);
}

static __device__ __forceinline__ void gload_lds16(const void* g, void* l) {
  __builtin_amdgcn_global_load_lds(
      (const __attribute__((address_space(1))) unsigned int*)g,
      (__attribute__((address_space(3))) unsigned int*)l, 16, 0, 0);
}

// ---------------------------------------------------------------------------
// f32 -> bf16 converts.
// ---------------------------------------------------------------------------
__global__ __launch_bounds__(256) void convert_x(
    const float4* __restrict__ x, ushort4* __restrict__ xh)
{
  int i = blockIdx.x * 256 + threadIdx.x;
  float4 v = x[i];
  ushort4 h;
  h.x = f2bf(v.x); h.y = f2bf(v.y); h.z = f2bf(v.z); h.w = f2bf(v.w);
  xh[i] = h;
}

__global__ __launch_bounds__(256) void convert_w4(
    const float4* __restrict__ w0, const float4* __restrict__ w1,
    const float4* __restrict__ w2, const float4* __restrict__ w3,
    ushort4* __restrict__ dst)
{
  const int z = blockIdx.y;
  const float4* __restrict__ src = (z == 0) ? w0 : (z == 1) ? w1 : (z == 2) ? w2 : w3;
  int i = blockIdx.x * 256 + threadIdx.x;
  float4 v = src[i];
  ushort4 h;
  h.x = f2bf(v.x); h.y = f2bf(v.y); h.z = f2bf(v.z); h.w = f2bf(v.w);
  dst[(size_t)z * (CC / 4) + i] = h;
}

// ---------------------------------------------------------------------------
// FAT-WAVE MFMA GEMM (NT), K=768, tile 256x256, BK=32, 256 threads
// (4 waves, 2M x 2N), per-wave 128x128 out: acc 8x8 f32x4 = 256 VGPR,
// ~350 total -> __launch_bounds__(256,1), 1 wave/SIMD. Rationale: R9-R14
// invariant at ~140us across ALL schedule knobs (barriers, occupancy,
// prefetch, blocks/CU) with per-wave 64x64..128x64 tiles; doubling
// per-wave output doubles FLOP per LDS byte (65.5 vs 32.8) -> per-phase
// 64-MFMA burst covers the 16 ds_read_b128 instead of vice versa. Total
// LDS traffic 4.8 -> 2.65 GB.
// Staging: sector-coalesced (4 lanes/row, 64B/row, chunk slot =
// kq ^ ((row>>1)&3) pre-applied to GLOBAL source, linear LDS dest).
// 8 gloads/thread/region; FIFO: prologue vmcnt(8); per-phase STG(p+2)
// then vmcnt(8) drains r(p+1); p=22 vmcnt(0).
// MODE 0: fused kvr, N=2304 over [Wk|Wv|Wr]; bf16 outs K/V/sigmoid->SR.
// MODE 1: out-GEMM, N=768, f32 out.
// ---------------------------------------------------------------------------
#define STG(R) do { if ((R) < 24) {                                        \
    const int rs_ = ((R) % 3) * 16384;  /* shorts */                       \
    const int ko_ = (R) * 32;                                              \
    short* d_ = lds + rs_ + wave * 512;                                    \
    gload_lds16(pAs + ko_,               d_);                              \
    gload_lds16(pAs +  64 * 768 + ko_,   d_ + 2048);                       \
    gload_lds16(pAs + 128 * 768 + ko_,   d_ + 4096);                       \
    gload_lds16(pAs + 192 * 768 + ko_,   d_ + 6144);                       \
    gload_lds16(pBs + ko_,               d_ + 8192);                       \
    gload_lds16(pBs +  64 * 768 + ko_,   d_ + 10240);                      \
    gload_lds16(pBs + 128 * 768 + ko_,   d_ + 12288);                      \
    gload_lds16(pBs + 192 * 768 + ko_,   d_ + 14336);                      \
  } } while (0)

#define RDF(R) do {                                                        \
    const int rb_ = ((R) % 3) * 32768;  /* bytes */                        \
    _Pragma("unroll")                                                      \
    for (int mi = 0; mi < 8; ++mi)                                         \
      a[mi] = *(const bf16x8*)(lds + ((rb_ + abase + mi * 1024) >> 1));    \
    _Pragma("unroll")                                                      \
    for (int ni = 0; ni < 8; ++ni)                                         \
      b[ni] = *(const bf16x8*)(lds + ((rb_ + bbase + ni * 1024) >> 1));    \
  } while (0)

#define MM()                                                               \
    _Pragma("unroll")                                                      \
    for (int mi = 0; mi < 8; ++mi)                                         \
      _Pragma("unroll")                                                    \
      for (int ni = 0; ni < 8; ++ni)                                       \
        acc[mi][ni] = __builtin_amdgcn_mfma_f32_16x16x32_bf16(             \
            a[mi], b[ni], acc[mi][ni], 0, 0, 0);

#define PH(P)                                                              \
  {                                                                        \
    RDF(P);                                                                \
    STG((P) + 2);                                                          \
    __builtin_amdgcn_sched_barrier(0);                                     \
    __builtin_amdgcn_s_setprio(1);                                         \
    MM()                                                                   \
    __builtin_amdgcn_s_setprio(0);                                         \
    if ((P) <= 21)      { asm volatile("s_waitcnt vmcnt(8)" ::: "memory"); } \
    else if ((P) == 22) { asm volatile("s_waitcnt vmcnt(0)" ::: "memory"); } \
    __builtin_amdgcn_s_barrier();                                          \
    __builtin_amdgcn_sched_barrier(0);                                     \
  }

template<int MODE>
__global__ __launch_bounds__(256, 1) void gemmFW(
    const short* __restrict__ A, const short* __restrict__ Wb,
    unsigned short* __restrict__ OK, unsigned short* __restrict__ OV,
    unsigned short* __restrict__ OSR, float* __restrict__ Oout)
{
  extern __shared__ short lds[];   // 96 KB = 3 regions x 32KB
  const int K = C_DIM;
  constexpr int NWN = (MODE == 0) ? 9 : 3;     // n-tiles of 256
  constexpr int CPX = (MODE == 0) ? 144 : 48;  // blocks per XCD (bijective)

  int f  = blockIdx.x + blockIdx.y * NWN;
  int wg = (f & 7) * CPX + (f >> 3);
  const int n0 = (wg % NWN) * 256;
  const int m0 = (wg / NWN) * 256;

  const int tid  = threadIdx.x;
  const int lane = tid & 63, wave = tid >> 6;
  const int wr = wave >> 1, wc = wave & 1;   // 2M x 2N wave grid
  const int lr = lane & 15, lk = lane >> 4;

  // fragment swizzle (lane-constant): slot = lk ^ ((lr>>1)&3)
  const int aswz = lk ^ ((lr >> 1) & 3);
  const int abase = (wr * 128 + lr) * 64 + aswz * 16;            // bytes
  const int bbase = 16384 + (wc * 128 + lr) * 64 + aswz * 16;    // bytes

  // staging sources: 4 lanes/row, 64B/row (chunk-permuted on source).
  const int srow = tid >> 2;                          // 0..63
  const int skq  = (tid & 3) ^ ((tid >> 3) & 3);
  const short* pAs = A  + (size_t)(m0 + srow) * K + skq * 8;
  const short* pBs = Wb + (size_t)(n0 + srow) * K + skq * 8;

  f32x4 acc[8][8];
#pragma unroll
  for (int i = 0; i < 8; ++i)
#pragma unroll
    for (int j = 0; j < 8; ++j) acc[i][j] = (f32x4){0.f, 0.f, 0.f, 0.f};

  bf16x8 a[8], b[8];

  // Prologue: stage regions 0,1; drain r0 (leave r1 in flight); barrier.
  STG(0); STG(1);
  asm volatile("s_waitcnt vmcnt(8)" ::: "memory");
  __builtin_amdgcn_s_barrier();
  __builtin_amdgcn_sched_barrier(0);

  // 24 phases, one BK=32 K-tile each.
#pragma unroll
  for (int p = 0; p < 24; ++p) PH(p)

  // Epilogue
  if (MODE == 0) {
    const int which = n0 / 768;               // 0:K 1:V 2:SR (all bf16 out)
    const int nc = (n0 % 768) + wc * 128;
    unsigned short* __restrict__ D = (which == 0) ? OK : (which == 1) ? OV : OSR;
#pragma unroll
    for (int mi = 0; mi < 8; ++mi)
#pragma unroll
      for (int ni = 0; ni < 8; ++ni) {
        const int row = m0 + wr * 128 + mi * 16 + lk * 4;
        const int col = nc + ni * 16 + lr;
#pragma unroll
        for (int j = 0; j < 4; ++j) {
          float v = acc[mi][ni][j];
          if (which == 2) v = 1.f / (1.f + __expf(-v));
          D[(size_t)(row + j) * C_DIM + col] = f2bf(v);
        }
      }
  } else {
#pragma unroll
    for (int mi = 0; mi < 8; ++mi)
#pragma unroll
      for (int ni = 0; ni < 8; ++ni) {
        const int row = m0 + wr * 128 + mi * 16 + lk * 4;
        const int col = n0 + wc * 128 + ni * 16 + lr;
#pragma unroll
        for (int j = 0; j < 4; ++j)
          Oout[(size_t)(row + j) * C_DIM + col] = acc[mi][ni][j];
      }
  }
}

// ---------------------------------------------------------------------------
// WKV chunk-parallel scan over bf16 K/V (R9/R10 proven versions).
// ---------------------------------------------------------------------------
#define P1_LOAD(kk_, vv_, base_)                                  \
  _Pragma("unroll") for (int j = 0; j < 8; ++j) {                 \
    int r_ = si[(base_) + j];                                     \
    kk_[j] = Kb[(size_t)r_ * C_DIM];                              \
    vv_[j] = Vb[(size_t)r_ * C_DIM];                              \
  }
#define P1_COMP(kk_, vv_)                                         \
  _Pragma("unroll") for (int j = 0; j < 8; ++j) {                 \
    float kt = bf2f(kk_[j]), vt = bf2f(vv_[j]);                   \
    float ww2 = w + pp; float p2 = fmaxf(ww2, kt);                \
    float e1b = __expf(ww2 - p2), e2b = __expf(kt - p2);          \
    aa = e1b * aa + e2b * vt; bb = e1b * bb + e2b; pp = p2;       \
  }

__global__ __launch_bounds__(256) void wkv_pass1(
    const unsigned short* __restrict__ Kin, const unsigned short* __restrict__ Vin,
    const int* __restrict__ sidx, const float* __restrict__ decay,
    float* __restrict__ aL, float* __restrict__ bL, float* __restrict__ pL)
{
  __shared__ int si[CHL];
  const int tid = threadIdx.x;
  const int ch = blockIdx.x, b = blockIdx.z;
  const int c = blockIdx.y * 256 + tid;
  if (tid < CHL) si[tid] = sidx[ch * CHL + tid];
  __syncthreads();
  const float w = decay[c] * (1.0f / (float)T_SEQ);
  const unsigned short* Kb = Kin + (size_t)b * T_SEQ * C_DIM + c;
  const unsigned short* Vb = Vin + (size_t)b * T_SEQ * C_DIM + c;
  float aa = 0.f, bb = 0.f, pp = -1e38f;
  unsigned short kA[8], vA[8], kB[8], vB[8];
  P1_LOAD(kA, vA, 0)
  for (int t0 = 0; t0 < CHL; t0 += 16) {
    P1_LOAD(kB, vB, t0 + 8)
    P1_COMP(kA, vA)
    if (t0 + 16 < CHL) { P1_LOAD(kA, vA, t0 + 16) }
    P1_COMP(kB, vB)
  }
  const int idx = (b * C_DIM + c) * NCH + ch;
  aL[idx] = aa; bL[idx] = bb; pL[idx] = pp;
}

// Serial scan over chunks per (b,c).
__global__ __launch_bounds__(256) void wkv_scan(
    const float* __restrict__ aL, const float* __restrict__ bL,
    const float* __restrict__ pL,
    float* __restrict__ aI, float* __restrict__ bI, float* __restrict__ pI,
    const float* __restrict__ decay)
{
  const int g = blockIdx.x * 256 + threadIdx.x;  // 0..6143 = b*C + c
  const int c = g % C_DIM;
  const float wL = decay[c] * ((float)CHL / (float)T_SEQ);
  float aa = 0.f, bb = 0.f, pp = -1e38f;
  const int base = g * NCH;
  for (int ch = 0; ch < NCH; ++ch) {
    aI[base + ch] = aa; bI[base + ch] = bb; pI[base + ch] = pp;
    float p1 = pp + wL;
    float p2 = pL[base + ch];
    float p  = fmaxf(p1, p2);
    float e1 = __expf(p1 - p), e2 = __expf(p2 - p);
    aa = e1 * aa + e2 * aL[base + ch];
    bb = e1 * bb + e2 * bL[base + ch];
    pp = p;
  }
}

// Pass 2: replay chunk with incoming state; y (bf16) scattered to natural order.
#define P2_LOAD(rr_, kk_, vv_, base_)                             \
  _Pragma("unroll") for (int j = 0; j < 8; ++j) {                 \
    int r_ = si[(base_) + j];                                     \
    rr_[j] = r_;                                                  \
    kk_[j] = Kb[(size_t)r_ * C_DIM];                              \
    vv_[j] = Vb[(size_t)r_ * C_DIM];                              \
  }
#define P2_COMP(rr_, kk_, vv_)                                    \
  _Pragma("unroll") for (int j = 0; j < 8; ++j) {                 \
    float kt = bf2f(kk_[j]), vt = bf2f(vv_[j]);                   \
    float ww = u + kt; float p = fmaxf(pp, ww);                   \
    float e1 = __expf(pp - p), e2 = __expf(ww - p);               \
    float y = (e1 * aa + e2 * vt) / (e1 * bb + e2);               \
    Yb[(size_t)rr_[j] * C_DIM] = f2bf(y);                         \
    float ww2 = w + pp; float p2 = fmaxf(ww2, kt);                \
    float e1b = __expf(ww2 - p2), e2b = __expf(kt - p2);          \
    aa = e1b * aa + e2b * vt; bb = e1b * bb + e2b; pp = p2;       \
  }

__global__ __launch_bounds__(256) void wkv_pass2(
    const unsigned short* __restrict__ Kin, const unsigned short* __restrict__ Vin,
    const int* __restrict__ sidx,
    const float* __restrict__ decay, const float* __restrict__ first,
    const float* __restrict__ aI, const float* __restrict__ bI,
    const float* __restrict__ pI, unsigned short* __restrict__ Y)
{
  __shared__ int si[CHL];
  const int tid = threadIdx.x;
  const int ch = blockIdx.x, b = blockIdx.z;
  const int c = blockIdx.y * 256 + tid;
  if (tid < CHL) si[tid] = sidx[ch * CHL + tid];
  __syncthreads();
  const float w = decay[c] * (1.0f / (float)T_SEQ);
  const float u = first[c] * (1.0f / (float)T_SEQ);
  const unsigned short* Kb = Kin + (size_t)b * T_SEQ * C_DIM + c;
  const unsigned short* Vb = Vin + (size_t)b * T_SEQ * C_DIM + c;
  unsigned short* Yb = Y + (size_t)b * T_SEQ * C_DIM + c;
  const int idx = (b * C_DIM + c) * NCH + ch;
  float aa = aI[idx], bb = bI[idx], pp = pI[idx];
  int rA[8], rB[8]; unsigned short kA[8], vA[8], kB[8], vB[8];
  P2_LOAD(rA, kA, vA, 0)
  for (int t0 = 0; t0 < CHL; t0 += 16) {
    P2_LOAD(rB, kB, vB, t0 + 8)
    P2_COMP(rA, kA, vA)
    if (t0 + 16 < CHL) { P2_LOAD(rA, kA, vA, t0 + 16) }
    P2_COMP(rB, kB, vB)
  }
}

// ---------------------------------------------------------------------------
// Row LayerNorm over C + sigmoid gate; bf16 in (Y, SR), bf16 out (G).
// ---------------------------------------------------------------------------
__global__ __launch_bounds__(256) void ln_gate(
    const unsigned short* __restrict__ Y, const unsigned short* __restrict__ SR,
    const float* __restrict__ gam, const float* __restrict__ bet,
    unsigned short* __restrict__ G)
{
  const size_t row = blockIdx.x;
  const unsigned short* x = Y + row * C_DIM;
  const unsigned short* sr = SR + row * C_DIM;
  unsigned short* go = G + row * C_DIM;
  const int tid = threadIdx.x;

  float vals[3];
  float s = 0.f, s2 = 0.f;
#pragma unroll
  for (int j = 0; j < 3; ++j) {
    float v = bf2f(x[tid + j * 256]);
    vals[j] = v;
    s += v; s2 += v * v;
  }
#pragma unroll
  for (int off = 32; off >= 1; off >>= 1) {
    s  += __shfl_xor(s, off, 64);
    s2 += __shfl_xor(s2, off, 64);
  }
  __shared__ float red[8];
  const int wid = tid >> 6;
  if ((tid & 63) == 0) { red[wid] = s; red[wid + 4] = s2; }
  __syncthreads();
  s  = red[0] + red[1] + red[2] + red[3];
  s2 = red[4] + red[5] + red[6] + red[7];

  const float mu   = s * (1.f / (float)C_DIM);
  const float var  = s2 * (1.f / (float)C_DIM) - mu * mu;
  const float rsig = rsqrtf(var + 1e-5f);

#pragma unroll
  for (int j = 0; j < 3; ++j) {
    const int cc = tid + j * 256;
    float yv = (vals[j] - mu) * rsig * gam[cc] + bet[cc];
    go[cc] = f2bf(yv * bf2f(sr[cc]));
  }
}

// ---------------------------------------------------------------------------
extern "C" void kernel_launch(void* const* d_in, const int* in_sizes, int n_in,
                              void* d_out, int out_size, void* d_ws, size_t ws_size,
                              hipStream_t stream) {
  const float* x     = (const float*)d_in[0];
  const int*   sidx  = (const int*)  d_in[1];
  const float* decay = (const float*)d_in[2];
  const float* first = (const float*)d_in[3];
  const float* Wk    = (const float*)d_in[4];
  const float* Wv    = (const float*)d_in[5];
  const float* Wr    = (const float*)d_in[6];
  const float* Wo    = (const float*)d_in[7];
  const float* ln_g  = (const float*)d_in[8];
  const float* ln_b  = (const float*)d_in[9];
  float* out = (float*)d_out;

  const size_t NE = (size_t)M_ROWS * C_DIM;  // 25165824
  // Workspace layout (~210 MB, R10 aliasing):
  short* Whs  = (short*)d_ws;                        // 4*CC bf16 [Wk|Wv|Wr|Wo]
  short* x_hi = Whs + 4 * (size_t)CC;                // NE bf16
  unsigned short* Ybuf = (unsigned short*)x_hi;      // alias: Y after kvr done
  unsigned short* Kbuf = (unsigned short*)(x_hi + NE);  // NE bf16
  unsigned short* Gbuf = Kbuf;                       // alias: after K dead
  unsigned short* Vbuf = Kbuf + NE;                  // NE bf16
  unsigned short* SRb  = Vbuf + NE;                  // NE bf16
  float* aL = (float*)(SRb + NE);                    // 6 x 196608 f32
  float* bL = aL + 196608;
  float* pL = bL + 196608;
  float* aI = pL + 196608;
  float* bI = aI + 196608;
  float* pI = bI + 196608;

  // Allow 96 KB dynamic LDS (idempotent, capture-safe).
  (void)hipFuncSetAttribute(reinterpret_cast<const void*>(&gemmFW<0>),
                            hipFuncAttributeMaxDynamicSharedMemorySize, 98304);
  (void)hipFuncSetAttribute(reinterpret_cast<const void*>(&gemmFW<1>),
                            hipFuncAttributeMaxDynamicSharedMemorySize, 98304);

  // 1) bf16 conversions
  convert_x<<<24576, 256, 0, stream>>>((const float4*)x, (ushort4*)x_hi);
  convert_w4<<<dim3(576, 4), 256, 0, stream>>>(
      (const float4*)Wk, (const float4*)Wv, (const float4*)Wr, (const float4*)Wo,
      (ushort4*)Whs);

  // 2) fused k|v|sr GEMM: M=32768, N=2304, K=768 (1152 blocks of 256^2)
  gemmFW<0><<<dim3(9, 128), 256, 98304, stream>>>(
      x_hi, Whs, Kbuf, Vbuf, SRb, nullptr);

  // 3) WKV: chunk transitions -> serial chunk scan -> replay with y output
  wkv_pass1<<<dim3(NCH, 3, B_DIM), 256, 0, stream>>>(Kbuf, Vbuf, sidx, decay, aL, bL, pL);
  wkv_scan<<<24, 256, 0, stream>>>(aL, bL, pL, aI, bI, pI, decay);
  wkv_pass2<<<dim3(NCH, 3, B_DIM), 256, 0, stream>>>(Kbuf, Vbuf, sidx, decay, first,
                                                     aI, bI, pI, Ybuf);
  // 4) LayerNorm + gate -> bf16 GEMM operand (G aliases K; K dead now)
  ln_gate<<<M_ROWS, 256, 0, stream>>>(Ybuf, SRb, ln_g, ln_b, Gbuf);
  // 5) out = G @ Wo^T (384 blocks of 256^2, f32 out)
  gemmFW<1><<<dim3(3, 128), 256, 98304, stream>>>(
      (const short*)Gbuf, Whs + 3 * (size_t)CC, nullptr, nullptr, nullptr, out);
}

// Round 16
// 310.168 us; speedup vs baseline: 1.1217x; 1.1217x over previous
//
#include <hip/hip_runtime.h>
#include <cstddef>
#include <cstdint>

#define B_DIM 8
#define T_SEQ 4096
#define C_DIM 768
#define M_ROWS (B_DIM * T_SEQ)   // 32768
#define CC (C_DIM * C_DIM)       // 589824
#define NCH 32
#define CHL (T_SEQ / NCH)        // 128

using bf16x8 = __attribute__((ext_vector_type(8))) short;
using f32x4  = __attribute__((ext_vector_type(4))) float;

static __device__ __forceinline__ unsigned short f2bf(float f) {
  unsigned int u = __float_as_uint(f);
  return (unsigned short)((u + 0x7fffu + ((u >> 16) & 1u)) >> 16);
}
static __device__ __forceinline__ float bf2f(unsigned short s) {
  return __uint_as_float(((unsigned int)s) << 16);
}

static __device__ __forceinline__ void gload_lds16(const void* g, void* l) {
  __builtin_amdgcn_global_load_lds(
      (const __attribute__((address_space(1))) unsigned int*)g,
      (__attribute__((address_space(3))) unsigned int*)l, 16, 0, 0);
}

// ---------------------------------------------------------------------------
// f32 -> bf16 converts.
// ---------------------------------------------------------------------------
__global__ __launch_bounds__(256) void convert_x(
    const float4* __restrict__ x, ushort4* __restrict__ xh)
{
  int i = blockIdx.x * 256 + threadIdx.x;
  float4 v = x[i];
  ushort4 h;
  h.x = f2bf(v.x); h.y = f2bf(v.y); h.z = f2bf(v.z); h.w = f2bf(v.w);
  xh[i] = h;
}

__global__ __launch_bounds__(256) void convert_w4(
    const float4* __restrict__ w0, const float4* __restrict__ w1,
    const float4* __restrict__ w2, const float4* __restrict__ w3,
    ushort4* __restrict__ dst)
{
  const int z = blockIdx.y;
  const float4* __restrict__ src = (z == 0) ? w0 : (z == 1) ? w1 : (z == 2) ? w2 : w3;
  int i = blockIdx.x * 256 + threadIdx.x;
  float4 v = src[i];
  ushort4 h;
  h.x = f2bf(v.x); h.y = f2bf(v.y); h.z = f2bf(v.z); h.w = f2bf(v.w);
  dst[(size_t)z * (CC / 4) + i] = h;
}

// ---------------------------------------------------------------------------
// 2-blocks/CU MFMA GEMM (NT), K=768, tile 256x128, BK=32, 256 threads
// (4 waves, 2M x 2N), per-wave 128x64 out (acc 8x4). LDS 72KB = 3 rotating
// regions x 24KB (A 16KB + B 8KB). Sector-coalesced staging: 4 lanes/row,
// 64B contiguous per row; chunk slot = kq ^ ((row>>1)&3), inverse applied
// on global source (both-sides rule). Region r staged at phase r-2 (6
// gloads/thread), drained by vmcnt(6) after MM, one barrier per phase.
// BEST MEASURED CONFIG (R13: kvr 140.9us, total 309.8us). The full knob
// matrix (barrier count, frag prefetch, blocks/CU, waves/SIMD, per-wave
// tile) is measured invariant-or-worse around this point.
// MODE 0: fused kvr, N=2304 over [Wk|Wv|Wr]; bf16 outs K/V/sigmoid->SR.
// MODE 1: out-GEMM, N=768, f32 out.
// ---------------------------------------------------------------------------
#define STG3(R) do { if ((R) < 24) {                                       \
    const int rbs_ = ((R) % 3) * 12288;  /* shorts */                      \
    const int ko_ = (R) * 32;                                              \
    short* da_ = lds + rbs_ + wave * 512;                                  \
    gload_lds16(pAs + ko_, da_);                                           \
    gload_lds16(pAs +  64 * 768 + ko_, da_ + 2048);                        \
    gload_lds16(pAs + 128 * 768 + ko_, da_ + 4096);                        \
    gload_lds16(pAs + 192 * 768 + ko_, da_ + 6144);                        \
    short* db_ = lds + rbs_ + 8192 + wave * 512;                           \
    gload_lds16(pBs + ko_, db_);                                           \
    gload_lds16(pBs +  64 * 768 + ko_, db_ + 2048);                        \
  } } while (0)

#define RDF(R) do {                                                        \
    const int rb_ = ((R) % 3) * 24576;  /* bytes */                        \
    _Pragma("unroll")                                                      \
    for (int mi = 0; mi < 8; ++mi)                                         \
      a[mi] = *(const bf16x8*)(lds + ((rb_ + abase + mi * 1024) >> 1));    \
    _Pragma("unroll")                                                      \
    for (int ni = 0; ni < 4; ++ni)                                         \
      b[ni] = *(const bf16x8*)(lds + ((rb_ + bbase + ni * 1024) >> 1));    \
  } while (0)

#define MM()                                                               \
    _Pragma("unroll")                                                      \
    for (int mi = 0; mi < 8; ++mi)                                         \
      _Pragma("unroll")                                                    \
      for (int ni = 0; ni < 4; ++ni)                                       \
        acc[mi][ni] = __builtin_amdgcn_mfma_f32_16x16x32_bf16(             \
            a[mi], b[ni], acc[mi][ni], 0, 0, 0);

#define PH3(P)                                                             \
  {                                                                        \
    RDF(P);                                                                \
    STG3((P) + 2);                                                         \
    __builtin_amdgcn_sched_barrier(0);                                     \
    __builtin_amdgcn_s_setprio(1);                                         \
    MM()                                                                   \
    __builtin_amdgcn_s_setprio(0);                                         \
    if ((P) <= 21)      { asm volatile("s_waitcnt vmcnt(6)" ::: "memory"); } \
    else if ((P) == 22) { asm volatile("s_waitcnt vmcnt(0)" ::: "memory"); } \
    __builtin_amdgcn_s_barrier();                                          \
    __builtin_amdgcn_sched_barrier(0);                                     \
  }

template<int MODE>
__global__ __launch_bounds__(256, 2) void gemmDB(
    const short* __restrict__ A, const short* __restrict__ Wb,
    unsigned short* __restrict__ OK, unsigned short* __restrict__ OV,
    unsigned short* __restrict__ OSR, float* __restrict__ Oout)
{
  extern __shared__ short lds[];   // 72 KB
  const int K = C_DIM;
  constexpr int NWN = (MODE == 0) ? 18 : 6;    // n-tiles of 128
  constexpr int CPX = (MODE == 0) ? 288 : 96;  // blocks per XCD (bijective)

  int f  = blockIdx.x + blockIdx.y * NWN;
  int wg = (f & 7) * CPX + (f >> 3);
  const int n0 = (wg % NWN) * 128;
  const int m0 = (wg / NWN) * 256;

  const int tid  = threadIdx.x;
  const int lane = tid & 63, wave = tid >> 6;
  const int wr = wave >> 1, wc = wave & 1;   // 2M x 2N wave grid
  const int lr = lane & 15, lk = lane >> 4;

  // fragment swizzle (lane-constant): slot = lk ^ ((lr>>1)&3)
  const int aswz = lk ^ ((lr >> 1) & 3);
  const int abase = (wr * 128 + lr) * 64 + aswz * 16;           // bytes
  const int bbase = 16384 + (wc * 64 + lr) * 64 + aswz * 16;    // bytes

  // staging sources: 4 lanes/row, 64B/row (chunk-permuted).
  const int srow = tid >> 2;                          // 0..63
  const int skq  = (tid & 3) ^ ((tid >> 3) & 3);
  const short* pAs = A  + (size_t)(m0 + srow) * K + skq * 8;
  const short* pBs = Wb + (size_t)(n0 + srow) * K + skq * 8;

  f32x4 acc[8][4];
#pragma unroll
  for (int i = 0; i < 8; ++i)
#pragma unroll
    for (int j = 0; j < 4; ++j) acc[i][j] = (f32x4){0.f, 0.f, 0.f, 0.f};

  bf16x8 a[8], b[4];

  // Prologue: stage regions 0,1; drain r0 (leave r1 in flight); barrier.
  STG3(0); STG3(1);
  asm volatile("s_waitcnt vmcnt(6)" ::: "memory");
  __builtin_amdgcn_s_barrier();
  __builtin_amdgcn_sched_barrier(0);

  // 24 phases, one BK=32 K-tile each.
#pragma unroll
  for (int p = 0; p < 24; ++p) PH3(p)

  // Epilogue
  if (MODE == 0) {
    const int which = n0 / 768;               // 0:K 1:V 2:SR (all bf16 out)
    const int nc = (n0 % 768) + wc * 64;
    unsigned short* __restrict__ D = (which == 0) ? OK : (which == 1) ? OV : OSR;
#pragma unroll
    for (int mi = 0; mi < 8; ++mi)
#pragma unroll
      for (int ni = 0; ni < 4; ++ni) {
        const int row = m0 + wr * 128 + mi * 16 + lk * 4;
        const int col = nc + ni * 16 + lr;
#pragma unroll
        for (int j = 0; j < 4; ++j) {
          float v = acc[mi][ni][j];
          if (which == 2) v = 1.f / (1.f + __expf(-v));
          D[(size_t)(row + j) * C_DIM + col] = f2bf(v);
        }
      }
  } else {
#pragma unroll
    for (int mi = 0; mi < 8; ++mi)
#pragma unroll
      for (int ni = 0; ni < 4; ++ni) {
        const int row = m0 + wr * 128 + mi * 16 + lk * 4;
        const int col = n0 + wc * 64 + ni * 16 + lr;
#pragma unroll
        for (int j = 0; j < 4; ++j)
          Oout[(size_t)(row + j) * C_DIM + col] = acc[mi][ni][j];
      }
  }
}

// ---------------------------------------------------------------------------
// WKV chunk-parallel scan over bf16 K/V (R9/R10 proven versions).
// ---------------------------------------------------------------------------
#define P1_LOAD(kk_, vv_, base_)                                  \
  _Pragma("unroll") for (int j = 0; j < 8; ++j) {                 \
    int r_ = si[(base_) + j];                                     \
    kk_[j] = Kb[(size_t)r_ * C_DIM];                              \
    vv_[j] = Vb[(size_t)r_ * C_DIM];                              \
  }
#define P1_COMP(kk_, vv_)                                         \
  _Pragma("unroll") for (int j = 0; j < 8; ++j) {                 \
    float kt = bf2f(kk_[j]), vt = bf2f(vv_[j]);                   \
    float ww2 = w + pp; float p2 = fmaxf(ww2, kt);                \
    float e1b = __expf(ww2 - p2), e2b = __expf(kt - p2);          \
    aa = e1b * aa + e2b * vt; bb = e1b * bb + e2b; pp = p2;       \
  }

__global__ __launch_bounds__(256) void wkv_pass1(
    const unsigned short* __restrict__ Kin, const unsigned short* __restrict__ Vin,
    const int* __restrict__ sidx, const float* __restrict__ decay,
    float* __restrict__ aL, float* __restrict__ bL, float* __restrict__ pL)
{
  __shared__ int si[CHL];
  const int tid = threadIdx.x;
  const int ch = blockIdx.x, b = blockIdx.z;
  const int c = blockIdx.y * 256 + tid;
  if (tid < CHL) si[tid] = sidx[ch * CHL + tid];
  __syncthreads();
  const float w = decay[c] * (1.0f / (float)T_SEQ);
  const unsigned short* Kb = Kin + (size_t)b * T_SEQ * C_DIM + c;
  const unsigned short* Vb = Vin + (size_t)b * T_SEQ * C_DIM + c;
  float aa = 0.f, bb = 0.f, pp = -1e38f;
  unsigned short kA[8], vA[8], kB[8], vB[8];
  P1_LOAD(kA, vA, 0)
  for (int t0 = 0; t0 < CHL; t0 += 16) {
    P1_LOAD(kB, vB, t0 + 8)
    P1_COMP(kA, vA)
    if (t0 + 16 < CHL) { P1_LOAD(kA, vA, t0 + 16) }
    P1_COMP(kB, vB)
  }
  const int idx = (b * C_DIM + c) * NCH + ch;
  aL[idx] = aa; bL[idx] = bb; pL[idx] = pp;
}

// Serial scan over chunks per (b,c).
__global__ __launch_bounds__(256) void wkv_scan(
    const float* __restrict__ aL, const float* __restrict__ bL,
    const float* __restrict__ pL,
    float* __restrict__ aI, float* __restrict__ bI, float* __restrict__ pI,
    const float* __restrict__ decay)
{
  const int g = blockIdx.x * 256 + threadIdx.x;  // 0..6143 = b*C + c
  const int c = g % C_DIM;
  const float wL = decay[c] * ((float)CHL / (float)T_SEQ);
  float aa = 0.f, bb = 0.f, pp = -1e38f;
  const int base = g * NCH;
  for (int ch = 0; ch < NCH; ++ch) {
    aI[base + ch] = aa; bI[base + ch] = bb; pI[base + ch] = pp;
    float p1 = pp + wL;
    float p2 = pL[base + ch];
    float p  = fmaxf(p1, p2);
    float e1 = __expf(p1 - p), e2 = __expf(p2 - p);
    aa = e1 * aa + e2 * aL[base + ch];
    bb = e1 * bb + e2 * bL[base + ch];
    pp = p;
  }
}

// Pass 2: replay chunk with incoming state; y (bf16) scattered to natural order.
#define P2_LOAD(rr_, kk_, vv_, base_)                             \
  _Pragma("unroll") for (int j = 0; j < 8; ++j) {                 \
    int r_ = si[(base_) + j];                                     \
    rr_[j] = r_;                                                  \
    kk_[j] = Kb[(size_t)r_ * C_DIM];                              \
    vv_[j] = Vb[(size_t)r_ * C_DIM];                              \
  }
#define P2_COMP(rr_, kk_, vv_)                                    \
  _Pragma("unroll") for (int j = 0; j < 8; ++j) {                 \
    float kt = bf2f(kk_[j]), vt = bf2f(vv_[j]);                   \
    float ww = u + kt; float p = fmaxf(pp, ww);                   \
    float e1 = __expf(pp - p), e2 = __expf(ww - p);               \
    float y = (e1 * aa + e2 * vt) / (e1 * bb + e2);               \
    Yb[(size_t)rr_[j] * C_DIM] = f2bf(y);                         \
    float ww2 = w + pp; float p2 = fmaxf(ww2, kt);                \
    float e1b = __expf(ww2 - p2), e2b = __expf(kt - p2);          \
    aa = e1b * aa + e2b * vt; bb = e1b * bb + e2b; pp = p2;       \
  }

__global__ __launch_bounds__(256) void wkv_pass2(
    const unsigned short* __restrict__ Kin, const unsigned short* __restrict__ Vin,
    const int* __restrict__ sidx,
    const float* __restrict__ decay, const float* __restrict__ first,
    const float* __restrict__ aI, const float* __restrict__ bI,
    const float* __restrict__ pI, unsigned short* __restrict__ Y)
{
  __shared__ int si[CHL];
  const int tid = threadIdx.x;
  const int ch = blockIdx.x, b = blockIdx.z;
  const int c = blockIdx.y * 256 + tid;
  if (tid < CHL) si[tid] = sidx[ch * CHL + tid];
  __syncthreads();
  const float w = decay[c] * (1.0f / (float)T_SEQ);
  const float u = first[c] * (1.0f / (float)T_SEQ);
  const unsigned short* Kb = Kin + (size_t)b * T_SEQ * C_DIM + c;
  const unsigned short* Vb = Vin + (size_t)b * T_SEQ * C_DIM + c;
  unsigned short* Yb = Y + (size_t)b * T_SEQ * C_DIM + c;
  const int idx = (b * C_DIM + c) * NCH + ch;
  float aa = aI[idx], bb = bI[idx], pp = pI[idx];
  int rA[8], rB[8]; unsigned short kA[8], vA[8], kB[8], vB[8];
  P2_LOAD(rA, kA, vA, 0)
  for (int t0 = 0; t0 < CHL; t0 += 16) {
    P2_LOAD(rB, kB, vB, t0 + 8)
    P2_COMP(rA, kA, vA)
    if (t0 + 16 < CHL) { P2_LOAD(rA, kA, vA, t0 + 16) }
    P2_COMP(rB, kB, vB)
  }
}

// ---------------------------------------------------------------------------
// Row LayerNorm over C + sigmoid gate; bf16 in (Y, SR), bf16 out (G).
// ---------------------------------------------------------------------------
__global__ __launch_bounds__(256) void ln_gate(
    const unsigned short* __restrict__ Y, const unsigned short* __restrict__ SR,
    const float* __restrict__ gam, const float* __restrict__ bet,
    unsigned short* __restrict__ G)
{
  const size_t row = blockIdx.x;
  const unsigned short* x = Y + row * C_DIM;
  const unsigned short* sr = SR + row * C_DIM;
  unsigned short* go = G + row * C_DIM;
  const int tid = threadIdx.x;

  float vals[3];
  float s = 0.f, s2 = 0.f;
#pragma unroll
  for (int j = 0; j < 3; ++j) {
    float v = bf2f(x[tid + j * 256]);
    vals[j] = v;
    s += v; s2 += v * v;
  }
#pragma unroll
  for (int off = 32; off >= 1; off >>= 1) {
    s  += __shfl_xor(s, off, 64);
    s2 += __shfl_xor(s2, off, 64);
  }
  __shared__ float red[8];
  const int wid = tid >> 6;
  if ((tid & 63) == 0) { red[wid] = s; red[wid + 4] = s2; }
  __syncthreads();
  s  = red[0] + red[1] + red[2] + red[3];
  s2 = red[4] + red[5] + red[6] + red[7];

  const float mu   = s * (1.f / (float)C_DIM);
  const float var  = s2 * (1.f / (float)C_DIM) - mu * mu;
  const float rsig = rsqrtf(var + 1e-5f);

#pragma unroll
  for (int j = 0; j < 3; ++j) {
    const int cc = tid + j * 256;
    float yv = (vals[j] - mu) * rsig * gam[cc] + bet[cc];
    go[cc] = f2bf(yv * bf2f(sr[cc]));
  }
}

// ---------------------------------------------------------------------------
extern "C" void kernel_launch(void* const* d_in, const int* in_sizes, int n_in,
                              void* d_out, int out_size, void* d_ws, size_t ws_size,
                              hipStream_t stream) {
  const float* x     = (const float*)d_in[0];
  const int*   sidx  = (const int*)  d_in[1];
  const float* decay = (const float*)d_in[2];
  const float* first = (const float*)d_in[3];
  const float* Wk    = (const float*)d_in[4];
  const float* Wv    = (const float*)d_in[5];
  const float* Wr    = (const float*)d_in[6];
  const float* Wo    = (const float*)d_in[7];
  const float* ln_g  = (const float*)d_in[8];
  const float* ln_b  = (const float*)d_in[9];
  float* out = (float*)d_out;

  const size_t NE = (size_t)M_ROWS * C_DIM;  // 25165824
  // Workspace layout (~210 MB, R10 aliasing):
  short* Whs  = (short*)d_ws;                        // 4*CC bf16 [Wk|Wv|Wr|Wo]
  short* x_hi = Whs + 4 * (size_t)CC;                // NE bf16
  unsigned short* Ybuf = (unsigned short*)x_hi;      // alias: Y after kvr done
  unsigned short* Kbuf = (unsigned short*)(x_hi + NE);  // NE bf16
  unsigned short* Gbuf = Kbuf;                       // alias: after K dead
  unsigned short* Vbuf = Kbuf + NE;                  // NE bf16
  unsigned short* SRb  = Vbuf + NE;                  // NE bf16
  float* aL = (float*)(SRb + NE);                    // 6 x 196608 f32
  float* bL = aL + 196608;
  float* pL = bL + 196608;
  float* aI = pL + 196608;
  float* bI = aI + 196608;
  float* pI = bI + 196608;

  // Allow 72 KB dynamic LDS (idempotent, capture-safe).
  (void)hipFuncSetAttribute(reinterpret_cast<const void*>(&gemmDB<0>),
                            hipFuncAttributeMaxDynamicSharedMemorySize, 73728);
  (void)hipFuncSetAttribute(reinterpret_cast<const void*>(&gemmDB<1>),
                            hipFuncAttributeMaxDynamicSharedMemorySize, 73728);

  // 1) bf16 conversions
  convert_x<<<24576, 256, 0, stream>>>((const float4*)x, (ushort4*)x_hi);
  convert_w4<<<dim3(576, 4), 256, 0, stream>>>(
      (const float4*)Wk, (const float4*)Wv, (const float4*)Wr, (const float4*)Wo,
      (ushort4*)Whs);

  // 2) fused k|v|sr GEMM: M=32768, N=2304, K=768 (2304 blocks of 256x128)
  gemmDB<0><<<dim3(18, 128), 256, 73728, stream>>>(
      x_hi, Whs, Kbuf, Vbuf, SRb, nullptr);

  // 3) WKV: chunk transitions -> serial chunk scan -> replay with y output
  wkv_pass1<<<dim3(NCH, 3, B_DIM), 256, 0, stream>>>(Kbuf, Vbuf, sidx, decay, aL, bL, pL);
  wkv_scan<<<24, 256, 0, stream>>>(aL, bL, pL, aI, bI, pI, decay);
  wkv_pass2<<<dim3(NCH, 3, B_DIM), 256, 0, stream>>>(Kbuf, Vbuf, sidx, decay, first,
                                                     aI, bI, pI, Ybuf);
  // 4) LayerNorm + gate -> bf16 GEMM operand (G aliases K; K dead now)
  ln_gate<<<M_ROWS, 256, 0, stream>>>(Ybuf, SRb, ln_g, ln_b, Gbuf);
  // 5) out = G @ Wo^T (768 blocks of 256x128, f32 out)
  gemmDB<1><<<dim3(6, 128), 256, 73728, stream>>>(
      (const short*)Gbuf, Whs + 3 * (size_t)CC, nullptr, nullptr, nullptr, out);
}